// Round 1
// baseline (744.694 us; speedup 1.0000x reference)
//
#include <hip/hip_runtime.h>

#define D 1024
#define S_LEN 8192
#define BATCH 4
#define NROWS (BATCH * S_LEN)

typedef unsigned short u16;
typedef __attribute__((ext_vector_type(8))) short short8;
typedef __attribute__((ext_vector_type(8))) unsigned short u16x8;
typedef __attribute__((ext_vector_type(4))) unsigned short u16x4;
typedef __attribute__((ext_vector_type(4))) float f32x4;

__device__ __forceinline__ float bf2f(u16 u) {
  return __builtin_bit_cast(float, ((unsigned)u) << 16);
}
__device__ __forceinline__ u16 f2bf(float f) {
  unsigned u = __builtin_bit_cast(unsigned, f);
  u += 0x7FFFu + ((u >> 16) & 1u);
  return (u16)(u >> 16);
}

// global -> LDS direct DMA, 16B per lane. LDS side is wave-uniform base + lane*16.
#define GLD16(gp, lp)                                                    \
  __builtin_amdgcn_global_load_lds(                                      \
      (__attribute__((address_space(1))) void*)(void*)(gp),              \
      (__attribute__((address_space(3))) void*)(void*)(lp), 16, 0, 0)

// ---------------- weight fp32 -> bf16 cast ----------------
__global__ __launch_bounds__(256) void tobf16_kernel(
    const float* __restrict__ src, u16* __restrict__ dst, int n4) {
  int t = blockIdx.x * 256 + threadIdx.x;
  if (t < n4) {
    float4 v = *(const float4*)&src[(size_t)t * 4];
    u16x4 o;
    o[0] = f2bf(v.x); o[1] = f2bf(v.y); o[2] = f2bf(v.z); o[3] = f2bf(v.w);
    *(u16x4*)&dst[(size_t)t * 4] = o;
  }
}

// ---------------- rope cos/sin table [S][256] ----------------
__global__ __launch_bounds__(256) void rope_table_kernel(
    float* __restrict__ ct, float* __restrict__ st) {
  int t = blockIdx.x * 256 + threadIdx.x;  // S*256 threads
  int s = t >> 8, j = t & 255;
  double invf = pow(10000.0, -(double)j / 256.0);  // inv_freq[j] = 10000^(-2j/512)
  float f = (float)((double)s * invf);
  ct[t] = cosf(f);
  st[t] = sinf(f);
}

// ---------------- layernorm, wave per row, fp32 in -> bf16 out ----------------
__global__ __launch_bounds__(256) void ln_kernel(
    const float* __restrict__ X, const float* __restrict__ g,
    const float* __restrict__ bb, u16* __restrict__ Xn) {
  const int wave = threadIdx.x >> 6, lane = threadIdx.x & 63;
  const int row = blockIdx.x * 4 + wave;
  const float* xr = X + (size_t)row * D;
  float4 v[4];
  float s = 0.f, sq = 0.f;
#pragma unroll
  for (int i = 0; i < 4; i++) {
    v[i] = *(const float4*)&xr[lane * 4 + i * 256];
    s += v[i].x + v[i].y + v[i].z + v[i].w;
    sq += v[i].x * v[i].x + v[i].y * v[i].y + v[i].z * v[i].z + v[i].w * v[i].w;
  }
#pragma unroll
  for (int off = 32; off > 0; off >>= 1) {
    s += __shfl_xor(s, off);
    sq += __shfl_xor(sq, off);
  }
  const float mu = s * (1.f / D);
  const float var = sq * (1.f / D) - mu * mu;
  const float rstd = rsqrtf(var + 1e-5f);
#pragma unroll
  for (int i = 0; i < 4; i++) {
    const int c = lane * 4 + i * 256;
    float4 gg = *(const float4*)&g[c];
    float4 bv = *(const float4*)&bb[c];
    u16x4 o;
    o[0] = f2bf((v[i].x - mu) * rstd * gg.x + bv.x);
    o[1] = f2bf((v[i].y - mu) * rstd * gg.y + bv.y);
    o[2] = f2bf((v[i].z - mu) * rstd * gg.z + bv.z);
    o[3] = f2bf((v[i].w - mu) * rstd * gg.w + bv.w);
    *(u16x4*)&Xn[(size_t)row * D + c] = o;
  }
}

// ---------------- MFMA GEMM: C[M,N] = A[M,K] * B[N,K]^T ----------------
// 128x128 tile, BK=32, 256 thr = 4 waves (2x2), each wave 64x64 via 4x4 MFMA 16x16x32.
// EPI 0: store bf16 C.  EPI 1: store fp32 C + Xres.
template <int EPI>
__global__ __launch_bounds__(256) void gemm_bt(
    const u16* __restrict__ A, const u16* __restrict__ Bm,
    u16* __restrict__ Cbf, const float* __restrict__ Xres,
    float* __restrict__ Cf, int K, int ldc) {
  __shared__ u16 As[128 * 32];
  __shared__ u16 Bs[128 * 32];
  const int tid = threadIdx.x;
  const int wave = tid >> 6, lane = tid & 63;
  const int wm = wave >> 1, wn = wave & 1;
  const int l15 = lane & 15, quad = lane >> 4;
  const int m0 = blockIdx.y * 128;
  const int n0 = blockIdx.x * 128;

  f32x4 acc[4][4] = {};

  const int cb = wave * 128 + lane;  // 16B-chunk index base; +i*64 per issue
  for (int k0 = 0; k0 < K; k0 += 32) {
    __syncthreads();  // previous iter's LDS readers done
#pragma unroll
    for (int i = 0; i < 2; i++) {
      const int c = cb + i * 64;           // 0..511
      const int row = c >> 2;              // 0..127
      const int kk = (c & 3) << 3;         // 0,8,16,24
      GLD16(&A[(size_t)(m0 + row) * K + k0 + kk], &As[c * 8]);
      GLD16(&Bm[(size_t)(n0 + row) * K + k0 + kk], &Bs[c * 8]);
    }
    __syncthreads();  // drains vmcnt(0): LDS staged
    short8 af[4], bfr[4];
#pragma unroll
    for (int i = 0; i < 4; i++)
      af[i] = *(const short8*)&As[(wm * 64 + i * 16 + l15) * 32 + quad * 8];
#pragma unroll
    for (int j = 0; j < 4; j++)
      bfr[j] = *(const short8*)&Bs[(wn * 64 + j * 16 + l15) * 32 + quad * 8];
#pragma unroll
    for (int i = 0; i < 4; i++)
#pragma unroll
      for (int j = 0; j < 4; j++)
        acc[i][j] = __builtin_amdgcn_mfma_f32_16x16x32_bf16(af[i], bfr[j],
                                                            acc[i][j], 0, 0, 0);
  }

  // C/D layout: col = lane&15, row = quad*4 + reg
#pragma unroll
  for (int i = 0; i < 4; i++) {
#pragma unroll
    for (int r = 0; r < 4; r++) {
      const int row = m0 + wm * 64 + i * 16 + quad * 4 + r;
#pragma unroll
      for (int j = 0; j < 4; j++) {
        const int col = n0 + wn * 64 + j * 16 + l15;
        const float vv = acc[i][j][r];
        if constexpr (EPI == 0) {
          Cbf[(size_t)row * ldc + col] = f2bf(vv);
        } else {
          Cf[(size_t)row * ldc + col] = vv + Xres[(size_t)row * ldc + col];
        }
      }
    }
  }
}

// ---------------- A = sum_s l2norm(rot(K)) * V, per batch ----------------
// grid: BATCH*64 blocks; each block: 128 rows (wave handles 32); lane owns 16 cols.
__global__ __launch_bounds__(256) void areduce_kernel(
    const u16* __restrict__ QKV, const float* __restrict__ ct,
    const float* __restrict__ st, float* __restrict__ Aout) {
  const int wave = threadIdx.x >> 6, lane = threadIdx.x & 63;
  const int b = blockIdx.x >> 6;
  const int chunk = blockIdx.x & 63;
  const int c0 = lane << 4;
  float acc[16];
#pragma unroll
  for (int i = 0; i < 16; i++) acc[i] = 0.f;

  for (int t = 0; t < 32; t++) {
    const int s = chunk * 128 + wave * 32 + t;
    const size_t base = ((size_t)b * S_LEN + s) * (3 * D);
    u16x8 ka = *(const u16x8*)&QKV[base + D + c0];
    u16x8 kb = *(const u16x8*)&QKV[base + D + c0 + 8];
    float kx[16];
#pragma unroll
    for (int i = 0; i < 8; i++) { kx[i] = bf2f(ka[i]); kx[8 + i] = bf2f(kb[i]); }
    if (lane < 32) {  // cols < 512: rotary
      const int jb = c0 >> 1;
      const float* cp = &ct[(size_t)s * 256 + jb];
      const float* sp = &st[(size_t)s * 256 + jb];
#pragma unroll
      for (int p = 0; p < 8; p++) {
        float cv = cp[p], sv = sp[p];
        float e = kx[2 * p], o = kx[2 * p + 1];
        kx[2 * p] = e * cv - o * sv;
        kx[2 * p + 1] = o * cv + e * sv;
      }
    }
    float sq = 0.f;
#pragma unroll
    for (int i = 0; i < 16; i++) sq += kx[i] * kx[i];
#pragma unroll
    for (int off = 32; off > 0; off >>= 1) sq += __shfl_xor(sq, off);
    const float rn = rsqrtf(sq + 1e-6f);
    u16x8 va = *(const u16x8*)&QKV[base + 2 * D + c0];
    u16x8 vb = *(const u16x8*)&QKV[base + 2 * D + c0 + 8];
#pragma unroll
    for (int i = 0; i < 8; i++) {
      acc[i] += kx[i] * rn * bf2f(va[i]);
      acc[8 + i] += kx[8 + i] * rn * bf2f(vb[i]);
    }
  }

  __shared__ float red[D];
  if (wave == 0) {
#pragma unroll
    for (int i = 0; i < 16; i++) red[c0 + i] = acc[i];
  }
  __syncthreads();
  for (int w = 1; w < 4; w++) {
    if (wave == w) {
#pragma unroll
      for (int i = 0; i < 16; i++) red[c0 + i] += acc[i];
    }
    __syncthreads();
  }
  const int tid = threadIdx.x;
#pragma unroll
  for (int i = 0; i < 4; i++)
    atomicAdd(&Aout[(b << 10) + tid * 4 + i], red[tid * 4 + i]);
}

// ---------------- Y = A[b] * l2norm(rot(Q)) -> bf16 ----------------
__global__ __launch_bounds__(256) void y_kernel(
    const u16* __restrict__ QKV, const float* __restrict__ ct,
    const float* __restrict__ st, const float* __restrict__ Ain,
    u16* __restrict__ Y) {
  const int wave = threadIdx.x >> 6, lane = threadIdx.x & 63;
  const int row = blockIdx.x * 4 + wave;
  const int b = row >> 13, s = row & (S_LEN - 1);
  const int c0 = lane << 4;
  const size_t base = (size_t)row * (3 * D);
  u16x8 qa = *(const u16x8*)&QKV[base + c0];
  u16x8 qb = *(const u16x8*)&QKV[base + c0 + 8];
  float qx[16];
#pragma unroll
  for (int i = 0; i < 8; i++) { qx[i] = bf2f(qa[i]); qx[8 + i] = bf2f(qb[i]); }
  if (lane < 32) {
    const int jb = c0 >> 1;
    const float* cp = &ct[(size_t)s * 256 + jb];
    const float* sp = &st[(size_t)s * 256 + jb];
#pragma unroll
    for (int p = 0; p < 8; p++) {
      float cv = cp[p], sv = sp[p];
      float e = qx[2 * p], o = qx[2 * p + 1];
      qx[2 * p] = e * cv - o * sv;
      qx[2 * p + 1] = o * cv + e * sv;
    }
  }
  float sq = 0.f;
#pragma unroll
  for (int i = 0; i < 16; i++) sq += qx[i] * qx[i];
#pragma unroll
  for (int off = 32; off > 0; off >>= 1) sq += __shfl_xor(sq, off);
  const float rn = rsqrtf(sq + 1e-6f);
  u16x8 oa, ob;
#pragma unroll
  for (int i = 0; i < 8; i++) {
    oa[i] = f2bf(Ain[(b << 10) + c0 + i] * qx[i] * rn);
    ob[i] = f2bf(Ain[(b << 10) + c0 + 8 + i] * qx[8 + i] * rn);
  }
  *(u16x8*)&Y[(size_t)row * D + c0] = oa;
  *(u16x8*)&Y[(size_t)row * D + c0 + 8] = ob;
}

extern "C" void kernel_launch(void* const* d_in, const int* in_sizes, int n_in,
                              void* d_out, int out_size, void* d_ws, size_t ws_size,
                              hipStream_t stream) {
  const float* X = (const float*)d_in[0];
  const float* W_in = (const float*)d_in[1];
  const float* W_out = (const float*)d_in[2];
  const float* ln_g = (const float*)d_in[3];
  const float* ln_b = (const float*)d_in[4];
  float* out = (float*)d_out;

  char* ws = (char*)d_ws;
  size_t off = 0;
  auto alloc = [&](size_t bytes) -> void* {
    void* p = ws + off;
    off += (bytes + 255) & ~(size_t)255;
    return p;
  };
  u16* QKV = (u16*)alloc((size_t)NROWS * 3 * D * 2);   // 192 MB
  u16* Xn = (u16*)alloc((size_t)NROWS * D * 2);        // 64 MB
  u16* Yb = (u16*)alloc((size_t)NROWS * D * 2);        // 64 MB
  u16* Winb = (u16*)alloc((size_t)3 * D * D * 2);      // 6 MB
  u16* Woutb = (u16*)alloc((size_t)D * D * 2);         // 2 MB
  float* ct = (float*)alloc((size_t)S_LEN * 256 * 4);  // 8 MB
  float* st = (float*)alloc((size_t)S_LEN * 256 * 4);  // 8 MB
  float* Aacc = (float*)alloc((size_t)BATCH * D * 4);  // 16 KB

  hipMemsetAsync(Aacc, 0, (size_t)BATCH * D * 4, stream);
  tobf16_kernel<<<3 * D * D / 1024, 256, 0, stream>>>(W_in, Winb, 3 * D * D / 4);
  tobf16_kernel<<<D * D / 1024, 256, 0, stream>>>(W_out, Woutb, D * D / 4);
  rope_table_kernel<<<S_LEN, 256, 0, stream>>>(ct, st);
  ln_kernel<<<NROWS / 4, 256, 0, stream>>>(X, ln_g, ln_b, Xn);

  dim3 g1(3 * D / 128, NROWS / 128);
  gemm_bt<0><<<g1, 256, 0, stream>>>(Xn, Winb, QKV, nullptr, nullptr, D, 3 * D);

  areduce_kernel<<<BATCH * 64, 256, 0, stream>>>(QKV, ct, st, Aacc);
  y_kernel<<<NROWS / 4, 256, 0, stream>>>(QKV, ct, st, Aacc, Yb);

  dim3 g2(D / 128, NROWS / 128);
  gemm_bt<1><<<g2, 256, 0, stream>>>(Yb, Woutb, nullptr, X, out, D, D);
}

// Round 2
// 670.487 us; speedup vs baseline: 1.1107x; 1.1107x over previous
//
#include <hip/hip_runtime.h>

#define D 1024
#define S_LEN 8192
#define BATCH 4
#define NROWS (BATCH * S_LEN)

typedef unsigned short u16;
typedef __attribute__((ext_vector_type(8))) short short8;
typedef __attribute__((ext_vector_type(8))) unsigned short u16x8;
typedef __attribute__((ext_vector_type(4))) unsigned short u16x4;
typedef __attribute__((ext_vector_type(4))) float f32x4;

__device__ __forceinline__ float bf2f(u16 u) {
  return __builtin_bit_cast(float, ((unsigned)u) << 16);
}
__device__ __forceinline__ u16 f2bf(float f) {
  unsigned u = __builtin_bit_cast(unsigned, f);
  u += 0x7FFFu + ((u >> 16) & 1u);
  return (u16)(u >> 16);
}

// global -> LDS direct DMA, 16B per lane. LDS side is wave-uniform base + lane*16.
#define GLD16(gp, lp)                                                    \
  __builtin_amdgcn_global_load_lds(                                      \
      (__attribute__((address_space(1))) void*)(void*)(gp),              \
      (__attribute__((address_space(3))) void*)(void*)(lp), 16, 0, 0)

// ---------------- weight fp32 -> bf16 cast ----------------
__global__ __launch_bounds__(256) void tobf16_kernel(
    const float* __restrict__ src, u16* __restrict__ dst, int n4) {
  int t = blockIdx.x * 256 + threadIdx.x;
  if (t < n4) {
    float4 v = *(const float4*)&src[(size_t)t * 4];
    u16x4 o;
    o[0] = f2bf(v.x); o[1] = f2bf(v.y); o[2] = f2bf(v.z); o[3] = f2bf(v.w);
    *(u16x4*)&dst[(size_t)t * 4] = o;
  }
}

// ---------------- rope cos/sin table [S][256], fp32 fast path ----------------
__global__ __launch_bounds__(256) void rope_table_kernel(
    float* __restrict__ ct, float* __restrict__ st) {
  int t = blockIdx.x * 256 + threadIdx.x;  // S*256 threads
  int s = t >> 8, j = t & 255;
  // inv_freq[j] = 10000^(-j/256) = exp2(-j * log2(10000)/256)
  float invf = exp2f((float)j * -0.0519051265f);
  float f = (float)s * invf;
  float sv, cv;
  sincosf(f, &sv, &cv);
  ct[t] = cv;
  st[t] = sv;
}

// ---------------- layernorm, wave per row, fp32 in -> bf16 out ----------------
__global__ __launch_bounds__(256) void ln_kernel(
    const float* __restrict__ X, const float* __restrict__ g,
    const float* __restrict__ bb, u16* __restrict__ Xn) {
  const int wave = threadIdx.x >> 6, lane = threadIdx.x & 63;
  const int row = blockIdx.x * 4 + wave;
  const float* xr = X + (size_t)row * D;
  float4 v[4];
  float s = 0.f, sq = 0.f;
#pragma unroll
  for (int i = 0; i < 4; i++) {
    v[i] = *(const float4*)&xr[lane * 4 + i * 256];
    s += v[i].x + v[i].y + v[i].z + v[i].w;
    sq += v[i].x * v[i].x + v[i].y * v[i].y + v[i].z * v[i].z + v[i].w * v[i].w;
  }
#pragma unroll
  for (int off = 32; off > 0; off >>= 1) {
    s += __shfl_xor(s, off);
    sq += __shfl_xor(sq, off);
  }
  const float mu = s * (1.f / D);
  const float var = sq * (1.f / D) - mu * mu;
  const float rstd = rsqrtf(var + 1e-5f);
#pragma unroll
  for (int i = 0; i < 4; i++) {
    const int c = lane * 4 + i * 256;
    float4 gg = *(const float4*)&g[c];
    float4 bv = *(const float4*)&bb[c];
    u16x4 o;
    o[0] = f2bf((v[i].x - mu) * rstd * gg.x + bv.x);
    o[1] = f2bf((v[i].y - mu) * rstd * gg.y + bv.y);
    o[2] = f2bf((v[i].z - mu) * rstd * gg.z + bv.z);
    o[3] = f2bf((v[i].w - mu) * rstd * gg.w + bv.w);
    *(u16x4*)&Xn[(size_t)row * D + c] = o;
  }
}

// ---------------- MFMA GEMM: C[M,N] = A[M,K] * B[N,K]^T ----------------
// 128x128 tile, BK=64, 256 thr = 4 waves (2x2), each wave 64x64 via 4x4 MFMA 16x16x32.
// LDS staging XOR-swizzled (kchunk ^= row&7) -> ds_read_b128 at free 2-way aliasing.
// EPI 0: LDS-transpose epilogue, 16B bf16 stores.  EPI 1: scalar fp32 + Xres.
template <int EPI>
__global__ __launch_bounds__(256) void gemm_bt(
    const u16* __restrict__ A, const u16* __restrict__ Bm,
    u16* __restrict__ Cbf, const float* __restrict__ Xres,
    float* __restrict__ Cf, int K, int ldc) {
  __shared__ u16 smem[2 * 128 * 64];  // 32 KB: As | Bs
  u16* As = smem;
  u16* Bs = smem + 128 * 64;
  const int tid = threadIdx.x;
  const int wave = tid >> 6, lane = tid & 63;
  const int wm = wave >> 1, wn = wave & 1;
  const int l15 = lane & 15, quad = lane >> 4;
  const int m0 = blockIdx.y * 128;
  const int n0 = blockIdx.x * 128;
  const int sw = l15 & 7;  // read-side XOR swizzle key

  f32x4 acc[4][4] = {};

  for (int k0 = 0; k0 < K; k0 += 64) {
    __syncthreads();  // previous iter's LDS readers done
#pragma unroll
    for (int i = 0; i < 4; i++) {
      const int c = i * 256 + tid;         // 0..1023 chunk slot
      const int row = c >> 3;              // 0..127
      const int g = (c & 7) ^ (row & 7);   // swizzled source k-chunk
      GLD16(&A[(size_t)(m0 + row) * K + k0 + g * 8], &As[c * 8]);
      GLD16(&Bm[(size_t)(n0 + row) * K + k0 + g * 8], &Bs[c * 8]);
    }
    __syncthreads();  // drains vmcnt(0): LDS staged
#pragma unroll
    for (int ks = 0; ks < 2; ks++) {
      short8 af[4], bfr[4];
#pragma unroll
      for (int i = 0; i < 4; i++)
        af[i] = *(const short8*)
            &As[(wm * 64 + i * 16 + l15) * 64 + (((ks * 4 + quad) ^ sw) << 3)];
#pragma unroll
      for (int j = 0; j < 4; j++)
        bfr[j] = *(const short8*)
            &Bs[(wn * 64 + j * 16 + l15) * 64 + (((ks * 4 + quad) ^ sw) << 3)];
#pragma unroll
      for (int i = 0; i < 4; i++)
#pragma unroll
        for (int j = 0; j < 4; j++)
          acc[i][j] = __builtin_amdgcn_mfma_f32_16x16x32_bf16(
              af[i], bfr[j], acc[i][j], 0, 0, 0);
    }
  }

  // C/D layout: col = lane&15, row = quad*4 + reg
  if constexpr (EPI == 0) {
    __syncthreads();  // all K-loop LDS reads done before reuse
    u16* my = smem + wave * 4096;  // this wave's 64x64 bf16 staging region
#pragma unroll
    for (int i = 0; i < 4; i++)
#pragma unroll
      for (int j = 0; j < 4; j++)
#pragma unroll
        for (int r = 0; r < 4; r++)
          my[(i * 16 + quad * 4 + r) * 64 + j * 16 + l15] = f2bf(acc[i][j][r]);
    __syncthreads();  // lgkmcnt drain (wave-local dep, barrier keeps it simple)
#pragma unroll
    for (int t = 0; t < 8; t++) {
      const int flat = t * 512 + lane * 8;  // u16 index within 64x64 tile
      const int r64 = flat >> 6, c64 = flat & 63;
      *(u16x8*)&Cbf[(size_t)(m0 + wm * 64 + r64) * ldc + n0 + wn * 64 + c64] =
          *(const u16x8*)&my[flat];
    }
  } else {
#pragma unroll
    for (int i = 0; i < 4; i++) {
#pragma unroll
      for (int r = 0; r < 4; r++) {
        const int row = m0 + wm * 64 + i * 16 + quad * 4 + r;
#pragma unroll
        for (int j = 0; j < 4; j++) {
          const int col = n0 + wn * 64 + j * 16 + l15;
          Cf[(size_t)row * ldc + col] =
              acc[i][j][r] + Xres[(size_t)row * ldc + col];
        }
      }
    }
  }
}

// ---------------- A = sum_s l2norm(rot(K)) * V, per batch ----------------
// grid: BATCH*256 blocks; each block: 32 rows (wave handles 8); lane owns 16 cols.
__global__ __launch_bounds__(256) void areduce_kernel(
    const u16* __restrict__ QKV, const float* __restrict__ ct,
    const float* __restrict__ st, float* __restrict__ Aout) {
  const int wave = threadIdx.x >> 6, lane = threadIdx.x & 63;
  const int b = blockIdx.x >> 8;
  const int chunk = blockIdx.x & 255;
  const int c0 = lane << 4;
  float acc[16];
#pragma unroll
  for (int i = 0; i < 16; i++) acc[i] = 0.f;

  for (int t = 0; t < 8; t++) {
    const int s = chunk * 32 + wave * 8 + t;
    const size_t base = ((size_t)b * S_LEN + s) * (3 * D);
    u16x8 ka = *(const u16x8*)&QKV[base + D + c0];
    u16x8 kb = *(const u16x8*)&QKV[base + D + c0 + 8];
    float kx[16];
#pragma unroll
    for (int i = 0; i < 8; i++) { kx[i] = bf2f(ka[i]); kx[8 + i] = bf2f(kb[i]); }
    if (lane < 32) {  // cols < 512: rotary
      const int jb = c0 >> 1;
      const float* cp = &ct[(size_t)s * 256 + jb];
      const float* sp = &st[(size_t)s * 256 + jb];
#pragma unroll
      for (int p = 0; p < 8; p++) {
        float cv = cp[p], sv = sp[p];
        float e = kx[2 * p], o = kx[2 * p + 1];
        kx[2 * p] = e * cv - o * sv;
        kx[2 * p + 1] = o * cv + e * sv;
      }
    }
    float sq = 0.f;
#pragma unroll
    for (int i = 0; i < 16; i++) sq += kx[i] * kx[i];
#pragma unroll
    for (int off = 32; off > 0; off >>= 1) sq += __shfl_xor(sq, off);
    const float rn = rsqrtf(sq + 1e-6f);
    u16x8 va = *(const u16x8*)&QKV[base + 2 * D + c0];
    u16x8 vb = *(const u16x8*)&QKV[base + 2 * D + c0 + 8];
#pragma unroll
    for (int i = 0; i < 8; i++) {
      acc[i] += kx[i] * rn * bf2f(va[i]);
      acc[8 + i] += kx[8 + i] * rn * bf2f(vb[i]);
    }
  }

  __shared__ float red[D];
  if (wave == 0) {
#pragma unroll
    for (int i = 0; i < 16; i++) red[c0 + i] = acc[i];
  }
  __syncthreads();
  for (int w = 1; w < 4; w++) {
    if (wave == w) {
#pragma unroll
      for (int i = 0; i < 16; i++) red[c0 + i] += acc[i];
    }
    __syncthreads();
  }
  const int tid = threadIdx.x;
#pragma unroll
  for (int i = 0; i < 4; i++)
    atomicAdd(&Aout[(b << 10) + tid * 4 + i], red[tid * 4 + i]);
}

// ---------------- Y = A[b] * l2norm(rot(Q)) -> bf16 ----------------
__global__ __launch_bounds__(256) void y_kernel(
    const u16* __restrict__ QKV, const float* __restrict__ ct,
    const float* __restrict__ st, const float* __restrict__ Ain,
    u16* __restrict__ Y) {
  const int wave = threadIdx.x >> 6, lane = threadIdx.x & 63;
  const int row = blockIdx.x * 4 + wave;
  const int b = row >> 13, s = row & (S_LEN - 1);
  const int c0 = lane << 4;
  const size_t base = (size_t)row * (3 * D);
  u16x8 qa = *(const u16x8*)&QKV[base + c0];
  u16x8 qb = *(const u16x8*)&QKV[base + c0 + 8];
  float qx[16];
#pragma unroll
  for (int i = 0; i < 8; i++) { qx[i] = bf2f(qa[i]); qx[8 + i] = bf2f(qb[i]); }
  if (lane < 32) {
    const int jb = c0 >> 1;
    const float* cp = &ct[(size_t)s * 256 + jb];
    const float* sp = &st[(size_t)s * 256 + jb];
#pragma unroll
    for (int p = 0; p < 8; p++) {
      float cv = cp[p], sv = sp[p];
      float e = qx[2 * p], o = qx[2 * p + 1];
      qx[2 * p] = e * cv - o * sv;
      qx[2 * p + 1] = o * cv + e * sv;
    }
  }
  float sq = 0.f;
#pragma unroll
  for (int i = 0; i < 16; i++) sq += qx[i] * qx[i];
#pragma unroll
  for (int off = 32; off > 0; off >>= 1) sq += __shfl_xor(sq, off);
  const float rn = rsqrtf(sq + 1e-6f);
  u16x8 oa, ob;
#pragma unroll
  for (int i = 0; i < 8; i++) {
    oa[i] = f2bf(Ain[(b << 10) + c0 + i] * qx[i] * rn);
    ob[i] = f2bf(Ain[(b << 10) + c0 + 8 + i] * qx[8 + i] * rn);
  }
  *(u16x8*)&Y[(size_t)row * D + c0] = oa;
  *(u16x8*)&Y[(size_t)row * D + c0 + 8] = ob;
}

extern "C" void kernel_launch(void* const* d_in, const int* in_sizes, int n_in,
                              void* d_out, int out_size, void* d_ws, size_t ws_size,
                              hipStream_t stream) {
  const float* X = (const float*)d_in[0];
  const float* W_in = (const float*)d_in[1];
  const float* W_out = (const float*)d_in[2];
  const float* ln_g = (const float*)d_in[3];
  const float* ln_b = (const float*)d_in[4];
  float* out = (float*)d_out;

  char* ws = (char*)d_ws;
  size_t off = 0;
  auto alloc = [&](size_t bytes) -> void* {
    void* p = ws + off;
    off += (bytes + 255) & ~(size_t)255;
    return p;
  };
  u16* QKV = (u16*)alloc((size_t)NROWS * 3 * D * 2);   // 192 MB
  u16* Xn = (u16*)alloc((size_t)NROWS * D * 2);        // 64 MB
  u16* Yb = (u16*)alloc((size_t)NROWS * D * 2);        // 64 MB
  u16* Winb = (u16*)alloc((size_t)3 * D * D * 2);      // 6 MB
  u16* Woutb = (u16*)alloc((size_t)D * D * 2);         // 2 MB
  float* ct = (float*)alloc((size_t)S_LEN * 256 * 4);  // 8 MB
  float* st = (float*)alloc((size_t)S_LEN * 256 * 4);  // 8 MB
  float* Aacc = (float*)alloc((size_t)BATCH * D * 4);  // 16 KB

  hipMemsetAsync(Aacc, 0, (size_t)BATCH * D * 4, stream);
  tobf16_kernel<<<3 * D * D / 1024, 256, 0, stream>>>(W_in, Winb, 3 * D * D / 4);
  tobf16_kernel<<<D * D / 1024, 256, 0, stream>>>(W_out, Woutb, D * D / 4);
  rope_table_kernel<<<S_LEN, 256, 0, stream>>>(ct, st);
  ln_kernel<<<NROWS / 4, 256, 0, stream>>>(X, ln_g, ln_b, Xn);

  dim3 g1(3 * D / 128, NROWS / 128);
  gemm_bt<0><<<g1, 256, 0, stream>>>(Xn, Winb, QKV, nullptr, nullptr, D, 3 * D);

  areduce_kernel<<<BATCH * 256, 256, 0, stream>>>(QKV, ct, st, Aacc);
  y_kernel<<<NROWS / 4, 256, 0, stream>>>(QKV, ct, st, Aacc, Yb);

  dim3 g2(D / 128, NROWS / 128);
  gemm_bt<1><<<g2, 256, 0, stream>>>(Yb, Woutb, nullptr, X, out, D, D);
}